// Round 3
// baseline (437.242 us; speedup 1.0000x reference)
//
#include <hip/hip_runtime.h>
#include <cstddef>

#define N_NODES 50000
#define N_EDGES 800000
#define N_GRAPHS 128
#define DIM 128
#define N_LAYERS 4
#define GN_EPS 1e-5f

// bucket-sort params
#define B_CHUNK 256        // chunk blocks
#define EPB 3125           // edges per chunk (256*3125 = 800000 exactly)
#define BUCKET_SHIFT 9
#define BUCKET_SIZE 512
#define NB 98              // ceil(50000/512)
#define SCAN_BLKS 25       // ceil(NB*B_CHUNK / 1024)

// setup_misc grid partition
#define CX_BLKS 12500      // convert_x: 50000*64 uints / 256
#define CW_BLKS 512        // convert_w: 8*128*128 / 256
#define GB_BLKS 196        // graph_bounds: ceil(50000/256)
#define SETUP_BLKS (CX_BLKS + CW_BLKS + GB_BLKS + B_CHUNK)

#define LG 8               // max graph-span per 256-row mm block (fast path)

typedef unsigned short ushort_t;
typedef __attribute__((ext_vector_type(8))) short frag8;
typedef __attribute__((ext_vector_type(4))) float f32x4;

__device__ inline float bfbits2f(unsigned hi16) { return __uint_as_float(hi16 << 16); }
__device__ inline ushort_t bf16rne(float v) {
    unsigned u = __float_as_uint(v);
    unsigned r = u + 0x7fff + ((u >> 16) & 1);
    return (ushort_t)(r >> 16);
}
__device__ inline unsigned packbf2(float a, float b) {
    return (unsigned)bf16rne(a) | ((unsigned)bf16rne(b) << 16);
}
__device__ inline void bf16split(float v, ushort_t& h, ushort_t& l) {
    ushort_t hi = bf16rne(v);
    float fh = __uint_as_float(((unsigned)hi) << 16);
    l = bf16rne(v - fh);
    h = hi;
}

// ---------------- merged independent setup: convert_x | convert_w | graph_bounds | p1_count ----
__global__ __launch_bounds__(256) void setup_misc(const float* __restrict__ x, unsigned* __restrict__ Hb,
                                                  const float* __restrict__ w1, const float* __restrict__ w2,
                                                  ushort_t* __restrict__ whi, ushort_t* __restrict__ wlo,
                                                  const int* __restrict__ batch, int* __restrict__ gstart,
                                                  const int* __restrict__ edst, int* __restrict__ cnts) {
    __shared__ int cnt[NB];
    int b = blockIdx.x, t = threadIdx.x;
    if (b < CX_BLKS) {
        int i = b * 256 + t;
        if (i < N_NODES * 64) {
            float a = x[2 * i], bb = x[2 * i + 1];
            Hb[i] = packbf2(a, bb);
        }
    } else if (b < CX_BLKS + CW_BLKS) {
        int idx = (b - CX_BLKS) * 256 + t;
        int mat = idx >> 14;
        int e = idx & 16383;
        int n = e >> 7, k = e & 127;
        int l = mat >> 1;
        const float* src = (mat & 1) ? (w2 + (size_t)l * DIM * DIM) : (w1 + (size_t)l * DIM * DIM);
        float v = src[k * DIM + n];
        ushort_t h, lw;
        bf16split(v, h, lw);
        whi[(size_t)mat * DIM * DIM + n * DIM + k] = h;
        wlo[(size_t)mat * DIM * DIM + n * DIM + k] = lw;
    } else if (b < CX_BLKS + CW_BLKS + GB_BLKS) {
        int i = (b - CX_BLKS - CW_BLKS) * 256 + t;
        if (i < N_NODES) {
            int bb = batch[i];
            if (i == 0) {
                for (int g = 0; g <= bb; ++g) gstart[g] = 0;
            } else {
                int pb = batch[i - 1];
                for (int g = pb + 1; g <= bb; ++g) gstart[g] = i;
            }
            if (i == N_NODES - 1) {
                for (int g = bb + 1; g <= N_GRAPHS; ++g) gstart[g] = N_NODES;
            }
        }
    } else {
        int blk = b - (CX_BLKS + CW_BLKS + GB_BLKS);
        for (int i = t; i < NB; i += 256) cnt[i] = 0;
        __syncthreads();
        int base = blk * EPB;
        for (int i = t; i < EPB; i += 256) atomicAdd(&cnt[edst[base + i] >> BUCKET_SHIFT], 1);
        __syncthreads();
        for (int i = t; i < NB; i += 256) cnts[i * B_CHUNK + blk] = cnt[i];
    }
}

// ---------------- scan phase 1 (over NB*B_CHUNK = 25088): block-local exclusive + block totals ----
__global__ __launch_bounds__(1024) void scan_local(const int* __restrict__ in, int* __restrict__ out,
                                                   int* __restrict__ bsum, int n) {
    __shared__ int wsum[16];
    int tid = threadIdx.x, lane = tid & 63, w = tid >> 6;
    int gi = blockIdx.x * 1024 + tid;
    int v = (gi < n) ? in[gi] : 0;
    int s = v;
    #pragma unroll
    for (int off = 1; off < 64; off <<= 1) {
        int t = __shfl_up(s, off, 64);
        if (lane >= off) s += t;
    }
    if (lane == 63) wsum[w] = s;
    __syncthreads();
    if (w == 0) {
        int ws = (lane < 16) ? wsum[lane] : 0;
        #pragma unroll
        for (int off = 1; off < 16; off <<= 1) {
            int t = __shfl_up(ws, off, 64);
            if (lane >= off) ws += t;
        }
        if (lane < 16) wsum[lane] = ws;
    }
    __syncthreads();
    int woff = (w > 0) ? wsum[w - 1] : 0;
    if (gi < n) out[gi] = woff + s - v;
    if (tid == 1023) bsum[blockIdx.x] = woff + s;
}

// ---------------- bucket CSR phase 3: place packed (dstfine<<16 | src); folds scan_add prefix --
__global__ __launch_bounds__(256) void p3_place(const int* __restrict__ src, const int* __restrict__ dst,
                                                const int* __restrict__ off, const int* __restrict__ bsum,
                                                unsigned* __restrict__ ebuf) {
    __shared__ int cur[NB];
    __shared__ int pexc[32];
    int t = threadIdx.x, blk = blockIdx.x;
    if (t < 32) {                       // exclusive prefix of the 25 scan-block totals
        int v = (t < SCAN_BLKS) ? bsum[t] : 0;
        int sI = v;
        #pragma unroll
        for (int o = 1; o < 32; o <<= 1) {
            int u = __shfl_up(sI, o, 64);
            if (t >= o) sI += u;
        }
        pexc[t] = sI - v;
    }
    __syncthreads();
    for (int i = t; i < NB; i += 256) {
        int j = i * B_CHUNK + blk;
        cur[i] = off[j] + pexc[j >> 10];
    }
    __syncthreads();
    int base = blk * EPB;
    for (int i = t; i < EPB; i += 256) {
        int d = dst[base + i];
        int b = d >> BUCKET_SHIFT;
        int pos = atomicAdd(&cur[b], 1);
        ebuf[pos] = (unsigned)src[base + i] | ((unsigned)(d & (BUCKET_SIZE - 1)) << 16);
    }
}

// ---------------- bucket CSR phase 4: per-bucket counting sort -> eoff + csr ----------------
__global__ __launch_bounds__(512) void p4_csr(const unsigned* __restrict__ ebuf, const int* __restrict__ off,
                                              const int* __restrict__ bsum,
                                              int* __restrict__ eoff, int* __restrict__ csr) {
    __shared__ int cnt[BUCKET_SIZE];
    __shared__ int wsum[8];
    __shared__ int pexc[32];
    int k = blockIdx.x, t = threadIdx.x;
    if (t < 32) {
        int v = (t < SCAN_BLKS) ? bsum[t] : 0;
        int sI = v;
        #pragma unroll
        for (int o = 1; o < 32; o <<= 1) {
            int u = __shfl_up(sI, o, 64);
            if (t >= o) sI += u;
        }
        pexc[t] = sI - v;
    }
    cnt[t] = 0;
    __syncthreads();
    int bstart = off[k * B_CHUNK] + pexc[(k * B_CHUNK) >> 10];
    int bend = (k == NB - 1) ? N_EDGES
                             : off[(k + 1) * B_CHUNK] + pexc[((k + 1) * B_CHUNK) >> 10];
    for (int i = bstart + t; i < bend; i += 512) atomicAdd(&cnt[ebuf[i] >> 16], 1);
    __syncthreads();
    int lane = t & 63, w = t >> 6;
    int v = cnt[t], s = v;
    #pragma unroll
    for (int o = 1; o < 64; o <<= 1) {
        int tt = __shfl_up(s, o, 64);
        if (lane >= o) s += tt;
    }
    if (lane == 63) wsum[w] = s;
    __syncthreads();
    if (w == 0) {
        int ws = (lane < 8) ? wsum[lane] : 0;
        #pragma unroll
        for (int o = 1; o < 8; o <<= 1) {
            int tt = __shfl_up(ws, o, 64);
            if (lane >= o) ws += tt;
        }
        if (lane < 8) wsum[lane] = ws;
    }
    __syncthreads();
    int woff = (w > 0) ? wsum[w - 1] : 0;
    int excl = woff + s - v;
    int node = k * BUCKET_SIZE + t;
    if (node < N_NODES) eoff[node] = bstart + excl;
    __syncthreads();
    cnt[t] = excl;  // reuse as cursor
    __syncthreads();
    for (int i = bstart + t; i < bend; i += 512) {
        unsigned p = ebuf[i];
        int pos = atomicAdd(&cnt[p >> 16], 1);
        csr[bstart + pos] = (int)(p & 0xffffu);
    }
    if (k == NB - 1 && t == 0) eoff[N_NODES] = N_EDGES;
}

// ---------------- GIN aggregation v4: quarter-wave edge parallelism, uint4 lanes ----------------
// One wave per node, 12.5k blocks: TLP averages out degree imbalance (round-1 lesson).
// First 128 blocks also zero the GraphNorm stats buffer for this layer's mm_layer.
__global__ __launch_bounds__(256) void agg_bf16(const uint4* __restrict__ h4, const int* __restrict__ eoff,
                                                const int* __restrict__ csr, uint4* __restrict__ T4,
                                                float* __restrict__ Sstat) {
    int zi = blockIdx.x * 256 + threadIdx.x;
    if (zi < 2 * N_GRAPHS * DIM) Sstat[zi] = 0.f;
    int wid = (blockIdx.x * 256 + threadIdx.x) >> 6;
    int lane = threadIdx.x & 63;
    int qtr = lane >> 4;
    int ql = lane & 15;
    if (wid >= N_NODES) return;
    int lo = eoff[wid], hi = eoff[wid + 1];

    float a[8];
    #pragma unroll
    for (int k = 0; k < 8; ++k) a[k] = 0.f;

    auto acc_row = [&](uint4 w) {
        a[0] += bfbits2f(w.x & 0xffffu); a[1] += bfbits2f(w.x >> 16);
        a[2] += bfbits2f(w.y & 0xffffu); a[3] += bfbits2f(w.y >> 16);
        a[4] += bfbits2f(w.z & 0xffffu); a[5] += bfbits2f(w.z >> 16);
        a[6] += bfbits2f(w.w & 0xffffu); a[7] += bfbits2f(w.w >> 16);
    };

    if (qtr == 0) acc_row(h4[(size_t)wid * 16 + ql]);  // self term

    for (int base = lo; base < hi; base += 64) {
        int nav = hi - base;
        if (nav > 64) nav = 64;
        int jv = (base + lane < hi) ? csr[base + lane] : 0;  // one coalesced index load
        int cmin = nav >> 2;
        int cmax = (nav + 3) >> 2;   // uniform loop bounds for the whole wave
        int i = 0;
        for (; i + 3 < cmin; i += 4) {  // 16 edges in flight across the wave
            int j0 = __shfl(jv, 4 * (i + 0) + qtr, 64);
            int j1 = __shfl(jv, 4 * (i + 1) + qtr, 64);
            int j2 = __shfl(jv, 4 * (i + 2) + qtr, 64);
            int j3 = __shfl(jv, 4 * (i + 3) + qtr, 64);
            uint4 w0 = h4[(size_t)j0 * 16 + ql];
            uint4 w1 = h4[(size_t)j1 * 16 + ql];
            uint4 w2 = h4[(size_t)j2 * 16 + ql];
            uint4 w3 = h4[(size_t)j3 * 16 + ql];
            acc_row(w0); acc_row(w1); acc_row(w2); acc_row(w3);
        }
        for (; i < cmin; ++i) {
            int j = __shfl(jv, 4 * i + qtr, 64);
            acc_row(h4[(size_t)j * 16 + ql]);
        }
        for (; i < cmax; ++i) {          // partial tail: shfl BEFORE the predicate
            int epos = 4 * i + qtr;
            int j = __shfl(jv, epos, 64);
            if (epos < nav) acc_row(h4[(size_t)j * 16 + ql]);
        }
    }

    #pragma unroll
    for (int k = 0; k < 8; ++k) {
        a[k] += __shfl_down(a[k], 32, 64);
        a[k] += __shfl_down(a[k], 16, 64);
    }
    if (qtr == 0) {
        uint4 o;
        o.x = packbf2(a[0], a[1]);
        o.y = packbf2(a[2], a[3]);
        o.z = packbf2(a[4], a[5]);
        o.w = packbf2(a[6], a[7]);
        T4[(size_t)wid * 16 + ql] = o;
    }
}

// ---------------- fused layer GEMM + GraphNorm stats: 256-row tile, 512 threads, ~106 KB LDS --
// Zb = relu(relu(T@W1+b1)@W2+b2); epilogue-2 also accumulates per-(graph,dim) sum/sumsq from
// the f32 register values (saves one full Zb read in the gn pass). Fast path: 16-row
// graph-uniform spans shfl-reduced over q, LDS atomics into lst[LG][DIM][2], one global flush.
__global__ __launch_bounds__(512) void mm_layer(const ushort_t* __restrict__ A,
                                                const ushort_t* __restrict__ W1h, const ushort_t* __restrict__ W1l,
                                                const ushort_t* __restrict__ W2h, const ushort_t* __restrict__ W2l,
                                                const float* __restrict__ b1, const float* __restrict__ b2,
                                                const int* __restrict__ batch,
                                                float* __restrict__ S1, float* __restrict__ S2,
                                                ushort_t* __restrict__ Zb) {
    __shared__ ushort_t As[256 * 128];   // 64 KB
    __shared__ ushort_t Ws[128 * 128];   // 32 KB
    __shared__ float lst[LG][DIM][2];    // 8 KB graph-local stats
    __shared__ int gmap[256];
    int tid = threadIdx.x;
    int row0 = blockIdx.x * 256;
    int wave = tid >> 6, lane = tid & 63;   // wave 0..7, each owns 32 rows
    int q = lane >> 4, mn = lane & 15;

    f32x4 acc[2][8];
    #pragma unroll
    for (int t = 0; t < 2; ++t)
        #pragma unroll
        for (int n = 0; n < 8; ++n) acc[t][n] = (f32x4)(0.f);

    // stage A: 256 rows x 16 uint4-chunks = 4096 chunks, 512 thr -> 8 iters
    #pragma unroll
    for (int i = 0; i < 8; ++i) {
        int c = tid + i * 512;
        int r = c >> 4, c8 = c & 15;
        uint4 v = make_uint4(0u, 0u, 0u, 0u);
        int gr = row0 + r;
        if (gr < N_NODES) v = *(const uint4*)(A + (size_t)gr * DIM + c8 * 8);
        *(uint4*)(&As[r * 128 + (c8 ^ (r & 7)) * 8]) = v;
    }
    // stats-scratch init (no barrier needed before: arrays untouched so far)
    if (tid < 256) {
        int gr = row0 + tid;
        gmap[tid] = batch[gr < N_NODES ? gr : (N_NODES - 1)];
    }
    for (int i = tid; i < LG * DIM * 2; i += 512) ((float*)lst)[i] = 0.f;

    auto stageW = [&](const ushort_t* src) {   // 2048 chunks, 512 thr -> 4 iters
        #pragma unroll
        for (int i = 0; i < 4; ++i) {
            int c = tid + i * 512;
            int r = c >> 4, c8 = c & 15;
            uint4 v = *(const uint4*)(src + r * DIM + c8 * 8);
            *(uint4*)(&Ws[r * 128 + (c8 ^ (r & 7)) * 8]) = v;
        }
    };
    auto compute = [&]() {
        #pragma unroll
        for (int ks = 0; ks < 4; ++ks) {
            int m0 = wave * 32 + mn;
            int m1 = m0 + 16;
            frag8 a0 = *(const frag8*)&As[m0 * 128 + (((ks * 4 + q) ^ (m0 & 7)) * 8)];
            frag8 a1 = *(const frag8*)&As[m1 * 128 + (((ks * 4 + q) ^ (m1 & 7)) * 8)];
            #pragma unroll
            for (int n = 0; n < 8; ++n) {
                int nr = n * 16 + mn;
                frag8 b = *(const frag8*)&Ws[nr * 128 + (((ks * 4 + q) ^ (nr & 7)) * 8)];
                acc[0][n] = __builtin_amdgcn_mfma_f32_16x16x32_bf16(a0, b, acc[0][n], 0, 0, 0);
                acc[1][n] = __builtin_amdgcn_mfma_f32_16x16x32_bf16(a1, b, acc[1][n], 0, 0, 0);
            }
        }
    };

    // ---- GEMM 1: Z1 = relu(A@W1 + b1) ----
    stageW(W1h);
    __syncthreads(); compute(); __syncthreads();
    stageW(W1l);
    __syncthreads(); compute(); __syncthreads();

    // epilogue 1: write bf16 Z1 back into As (swizzled), reset acc
    int mloc = wave * 32;
    #pragma unroll
    for (int t = 0; t < 2; ++t) {
        #pragma unroll
        for (int n = 0; n < 8; ++n) {
            int col = n * 16 + mn;
            float bv = b1[col];
            #pragma unroll
            for (int r = 0; r < 4; ++r) {
                int rloc = mloc + t * 16 + q * 4 + r;
                float v = fmaxf(acc[t][n][r] + bv, 0.f);
                As[rloc * 128 + ((col >> 3) ^ (rloc & 7)) * 8 + (col & 7)] = bf16rne(v);
                acc[t][n][r] = 0.f;
            }
        }
    }
    __syncthreads();
    // ---- GEMM 2: Z = relu(Z1@W2 + b2) ----
    stageW(W2h);
    __syncthreads(); compute(); __syncthreads();
    stageW(W2l);
    __syncthreads(); compute();

    int gbase = gmap[0];
    // epilogue 2: bf16 streaming store + stats accumulation
    #pragma unroll
    for (int t = 0; t < 2; ++t) {
        #pragma unroll
        for (int n = 0; n < 8; ++n) {
            int col = n * 16 + mn;
            float bv = b2[col];
            float vv[4];
            #pragma unroll
            for (int r = 0; r < 4; ++r) {
                int rloc = mloc + t * 16 + q * 4 + r;
                int grow = row0 + rloc;
                float v = fmaxf(acc[t][n][r] + bv, 0.f);
                vv[r] = v;
                if (grow < N_NODES)
                    Zb[(size_t)grow * DIM + col] = bf16rne(v);
            }
            int rb = mloc + t * 16;  // wave-uniform 16-row span
            bool span16 = (row0 + rb + 15 < N_NODES) && (gmap[rb] == gmap[rb + 15]);
            if (span16) {
                float s = vv[0] + vv[1] + vv[2] + vv[3];
                float s2 = vv[0]*vv[0] + vv[1]*vv[1] + vv[2]*vv[2] + vv[3]*vv[3];
                s += __shfl_xor(s, 16, 64);  s += __shfl_xor(s, 32, 64);
                s2 += __shfl_xor(s2, 16, 64); s2 += __shfl_xor(s2, 32, 64);
                if (q == 0) {
                    int lg = gmap[rb] - gbase;
                    if (lg < LG) {
                        atomicAdd(&lst[lg][col][0], s);
                        atomicAdd(&lst[lg][col][1], s2);
                    } else {
                        atomicAdd(&S1[gmap[rb] * DIM + col], s);
                        atomicAdd(&S2[gmap[rb] * DIM + col], s2);
                    }
                }
            } else {
                #pragma unroll
                for (int r = 0; r < 4; ++r) {
                    int rl = rb + q * 4 + r;
                    int grow = row0 + rl;
                    if (grow < N_NODES) {
                        int g = gmap[rl];
                        int lg = g - gbase;
                        float v = vv[r];
                        if (lg >= 0 && lg < LG) {
                            atomicAdd(&lst[lg][col][0], v);
                            atomicAdd(&lst[lg][col][1], v * v);
                        } else {
                            atomicAdd(&S1[g * DIM + col], v);
                            atomicAdd(&S2[g * DIM + col], v * v);
                        }
                    }
                }
            }
        }
    }
    __syncthreads();
    // flush block-local stats to global
    for (int i = tid; i < LG * DIM; i += 512) {
        int lg = i >> 7, d = i & 127;
        float a1 = lst[lg][d][0], a2 = lst[lg][d][1];
        if (a1 != 0.f || a2 != 0.f) {
            int g = gbase + lg;
            atomicAdd(&S1[g * DIM + d], a1);
            atomicAdd(&S2[g * DIM + d], a2);
        }
    }
}

// ---------------- flat GraphNorm normalize (non-last): 3125 blocks, one uint4/thread ---------
__global__ __launch_bounds__(256) void gn_norm(const uint4* __restrict__ Zb4,
                                               const float* __restrict__ S1, const float* __restrict__ S2,
                                               const int* __restrict__ batch, const int* __restrict__ gstart,
                                               const float* __restrict__ scale, const float* __restrict__ weight,
                                               const float* __restrict__ bias,
                                               uint4* __restrict__ Hb4) {
    int idx = blockIdx.x * 256 + threadIdx.x;   // exactly N_NODES*16 = 800000 items
    int n = idx >> 4, c = idx & 15, d0 = c * 8;
    int g = batch[n];
    int cnt = gstart[g + 1] - gstart[g];
    float cf = (float)(cnt > 0 ? cnt : 1);
    uint4 zz = Zb4[idx];
    unsigned zw[4] = {zz.x, zz.y, zz.z, zz.w};
    const float* s1p = S1 + (size_t)g * DIM + d0;
    const float* s2p = S2 + (size_t)g * DIM + d0;
    unsigned ow[4];
    #pragma unroll
    for (int p = 0; p < 4; ++p) {
        float o2[2];
        #pragma unroll
        for (int h = 0; h < 2; ++h) {
            int j = p * 2 + h;
            float m = s1p[j] / cf, ez = s2p[j] / cf;
            float sc = scale[d0 + j];
            float var = fmaxf(ez - (2.0f - sc) * sc * m * m, 0.f);
            float av = m * sc;
            float bm = weight[d0 + j] / sqrtf(var + GN_EPS);
            float z = bfbits2f(h ? (zw[p] >> 16) : (zw[p] & 0xffffu));
            o2[h] = fmaxf((z - av) * bm + bias[d0 + j], 0.f);
        }
        ow[p] = packbf2(o2[0], o2[1]);
    }
    uint4 o;
    o.x = ow[0]; o.y = ow[1]; o.z = ow[2]; o.w = ow[3];
    Hb4[idx] = o;
}

// ---------------- last layer: GraphNorm(coef from stats) + relu + readout + MLP + log_softmax --
__global__ __launch_bounds__(1024) void gn_last(const unsigned* __restrict__ Zb, const int* __restrict__ gstart,
                                                const float* __restrict__ S1, const float* __restrict__ S2,
                                                const float* __restrict__ scale, const float* __restrict__ weight,
                                                const float* __restrict__ bias,
                                                const float* __restrict__ fw1, const float* __restrict__ fb1,
                                                const float* __restrict__ fw2, const float* __restrict__ fb2,
                                                const float* __restrict__ fw3, const float* __restrict__ fb3,
                                                float* __restrict__ out) {
    __shared__ f32x4 sh1[1024];
    __shared__ float sa[128], sb[128];
    __shared__ float v0[128], v1[128], v2[128], lg[10];
    int g = blockIdx.x;
    int t = threadIdx.x;
    int du = t & 31, rg = t >> 5;            // 32 uint2-cols x 32 row-groups
    int s = gstart[g], e = gstart[g + 1];
    int dbase = du * 4;
    if (rg == 0) {                            // coefs straight from fused stats
        int cnt = e - s;
        float cf = (float)(cnt > 0 ? cnt : 1);
        #pragma unroll
        for (int j = 0; j < 4; ++j) {
            int d = dbase + j;
            float m = S1[(size_t)g * DIM + d] / cf;
            float ez = S2[(size_t)g * DIM + d] / cf;
            float sc = scale[d];
            float var = fmaxf(ez - (2.0f - sc) * sc * m * m, 0.f);
            sa[d] = m * sc;
            sb[d] = weight[d] / sqrtf(var + GN_EPS);
        }
    }
    __syncthreads();
    float as_[4], bm_[4], bi_[4];
    #pragma unroll
    for (int j = 0; j < 4; ++j) {
        as_[j] = sa[dbase + j];
        bm_[j] = sb[dbase + j];
        bi_[j] = bias[dbase + j];
    }
    const unsigned* zp = Zb + du * 2;
    f32x4 rsum = (f32x4)(0.f);
    for (int n = s + rg; n < e; n += 32) {
        uint2 zz = *(const uint2*)(zp + (size_t)n * 64);
        float z0 = bfbits2f(zz.x & 0xffffu), z1 = bfbits2f(zz.x >> 16);
        float z2 = bfbits2f(zz.y & 0xffffu), z3 = bfbits2f(zz.y >> 16);
        rsum[0] += fmaxf((z0 - as_[0]) * bm_[0] + bi_[0], 0.f);
        rsum[1] += fmaxf((z1 - as_[1]) * bm_[1] + bi_[1], 0.f);
        rsum[2] += fmaxf((z2 - as_[2]) * bm_[2] + bi_[2], 0.f);
        rsum[3] += fmaxf((z3 - as_[3]) * bm_[3] + bi_[3], 0.f);
    }
    sh1[t] = rsum;
    __syncthreads();
    if (rg == 0) {
        #pragma unroll 8
        for (int k = 1; k < 32; ++k) rsum += sh1[du + 32 * k];
        #pragma unroll
        for (int j = 0; j < 4; ++j) v0[dbase + j] = rsum[j];
    }
    __syncthreads();
    if (t < 128) {
        float acc = fb1[t];
        for (int d = 0; d < 128; ++d) acc += v0[d] * fw1[d * 128 + t];
        v1[t] = fmaxf(acc, 0.f);
    }
    __syncthreads();
    if (t < 128) {
        float acc = fb2[t];
        for (int d = 0; d < 128; ++d) acc += v1[d] * fw2[d * 128 + t];
        v2[t] = fmaxf(acc, 0.f);
    }
    __syncthreads();
    if (t < 10) {
        float acc = fb3[t];
        for (int d = 0; d < 128; ++d) acc += v2[d] * fw3[d * 10 + t];
        lg[t] = acc;
    }
    __syncthreads();
    if (t < 10) {
        float m = -1e30f;
        for (int c = 0; c < 10; ++c) m = fmaxf(m, lg[c]);
        float ssum = 0.f;
        for (int c = 0; c < 10; ++c) ssum += expf(lg[c] - m);
        out[g * 10 + t] = lg[t] - m - logf(ssum);
    }
}

extern "C" void kernel_launch(void* const* d_in, const int* in_sizes, int n_in,
                              void* d_out, int out_size, void* d_ws, size_t ws_size,
                              hipStream_t stream) {
    const float* x      = (const float*)d_in[0];
    const float* gin_w1 = (const float*)d_in[1];
    const float* gin_b1 = (const float*)d_in[2];
    const float* gin_w2 = (const float*)d_in[3];
    const float* gin_b2 = (const float*)d_in[4];
    const float* gn_w   = (const float*)d_in[5];
    const float* gn_b   = (const float*)d_in[6];
    const float* gn_s   = (const float*)d_in[7];
    const float* fw1    = (const float*)d_in[8];
    const float* fb1    = (const float*)d_in[9];
    const float* fw2    = (const float*)d_in[10];
    const float* fb2    = (const float*)d_in[11];
    const float* fw3    = (const float*)d_in[12];
    const float* fb3    = (const float*)d_in[13];
    const int*   eidx   = (const int*)d_in[14];
    const int*   batch  = (const int*)d_in[15];
    float* out = (float*)d_out;

    const int* esrc = eidx;
    const int* edst = eidx + N_EDGES;

    auto align_up = [](size_t v) { return (v + 255) & ~(size_t)255; };
    char* p = (char*)d_ws;
    unsigned* Hb = (unsigned*)p;   p += align_up((size_t)N_NODES * DIM * 2);
    unsigned* Tb = (unsigned*)p;   p += align_up((size_t)N_NODES * DIM * 2);
    unsigned* Zb = (unsigned*)p;   p += align_up((size_t)N_NODES * DIM * 2);
    ushort_t* WThi = (ushort_t*)p; p += align_up((size_t)8 * DIM * DIM * 2);
    ushort_t* WTlo = (ushort_t*)p; p += align_up((size_t)8 * DIM * DIM * 2);
    float* Sstat = (float*)p;      p += align_up((size_t)2 * N_GRAPHS * DIM * 4);
    int* gstart = (int*)p;         p += align_up((N_GRAPHS + 1) * 4);
    int* cnts = (int*)p;           p += align_up((size_t)NB * B_CHUNK * 4);
    int* off = (int*)p;            p += align_up(((size_t)NB * B_CHUNK + 1) * 4);
    int* bsum = (int*)p;           p += align_up(64 * 4);
    unsigned* ebuf = (unsigned*)p; p += align_up((size_t)N_EDGES * 4);
    int* eoff = (int*)p;           p += align_up((N_NODES + 1) * 4);
    int* csr = (int*)p;            p += align_up((size_t)N_EDGES * 4);

    float* S1 = Sstat;
    float* S2 = Sstat + N_GRAPHS * DIM;

    const int SCAN_N = NB * B_CHUNK;                      // 25088
    setup_misc<<<SETUP_BLKS, 256, 0, stream>>>(x, Hb, gin_w1, gin_w2, WThi, WTlo,
                                               batch, gstart, edst, cnts);
    scan_local<<<SCAN_BLKS, 1024, 0, stream>>>(cnts, off, bsum, SCAN_N);
    p3_place<<<B_CHUNK, 256, 0, stream>>>(esrc, edst, off, bsum, ebuf);
    p4_csr<<<NB, 512, 0, stream>>>(ebuf, off, bsum, eoff, csr);

    const int mm_grid = (N_NODES + 255) / 256;  // 196 blocks <= 256 CUs
    for (int l = 0; l < N_LAYERS; ++l) {
        agg_bf16<<<(N_NODES + 3) / 4, 256, 0, stream>>>((const uint4*)Hb, eoff, csr, (uint4*)Tb, Sstat);
        mm_layer<<<mm_grid, 512, 0, stream>>>((const ushort_t*)Tb,
            WThi + (size_t)(2 * l) * DIM * DIM, WTlo + (size_t)(2 * l) * DIM * DIM,
            WThi + (size_t)(2 * l + 1) * DIM * DIM, WTlo + (size_t)(2 * l + 1) * DIM * DIM,
            gin_b1 + l * DIM, gin_b2 + l * DIM, batch, S1, S2, (ushort_t*)Zb);
        if (l == N_LAYERS - 1)
            gn_last<<<N_GRAPHS, 1024, 0, stream>>>(Zb, gstart, S1, S2, gn_s + l * DIM,
                gn_w + l * DIM, gn_b + l * DIM, fw1, fb1, fw2, fb2, fw3, fb3, out);
        else
            gn_norm<<<(N_NODES * 16) / 256, 256, 0, stream>>>((const uint4*)Zb, S1, S2,
                batch, gstart, gn_s + l * DIM, gn_w + l * DIM, gn_b + l * DIM, (uint4*)Hb);
    }
}

// Round 4
// 380.949 us; speedup vs baseline: 1.1478x; 1.1478x over previous
//
#include <hip/hip_runtime.h>
#include <cstddef>

#define N_NODES 50000
#define N_EDGES 800000
#define N_GRAPHS 128
#define DIM 128
#define N_LAYERS 4
#define GN_EPS 1e-5f

// bucket-sort params
#define B_CHUNK 256        // chunk blocks
#define EPB 3125           // edges per chunk (256*3125 = 800000 exactly)
#define BUCKET_SHIFT 9
#define BUCKET_SIZE 512
#define NB 98              // ceil(50000/512)
#define SCAN_BLKS 25       // ceil(NB*B_CHUNK / 1024)

// setup_misc grid partition
#define CX_BLKS 3125       // convert_x vectorized: 50000*16 uint4 / 256
#define CW_BLKS 512        // convert_w: 8*128*128 / 256
#define GB_BLKS 196        // graph_bounds: ceil(50000/256)
#define SETUP_BLKS (CX_BLKS + CW_BLKS + GB_BLKS + B_CHUNK)

typedef unsigned short ushort_t;
typedef __attribute__((ext_vector_type(8))) short frag8;
typedef __attribute__((ext_vector_type(4))) float f32x4;

__device__ inline float bfbits2f(unsigned hi16) { return __uint_as_float(hi16 << 16); }
__device__ inline ushort_t bf16rne(float v) {
    unsigned u = __float_as_uint(v);
    unsigned r = u + 0x7fff + ((u >> 16) & 1);
    return (ushort_t)(r >> 16);
}
__device__ inline unsigned packbf2(float a, float b) {
    return (unsigned)bf16rne(a) | ((unsigned)bf16rne(b) << 16);
}
__device__ inline void bf16split(float v, ushort_t& h, ushort_t& l) {
    ushort_t hi = bf16rne(v);
    float fh = __uint_as_float(((unsigned)hi) << 16);
    l = bf16rne(v - fh);
    h = hi;
}

// ---------------- merged independent setup: convert_x | convert_w | graph_bounds | p1_count ----
__global__ __launch_bounds__(256) void setup_misc(const float4* __restrict__ x4, uint4* __restrict__ Hb4,
                                                  const float* __restrict__ w1, const float* __restrict__ w2,
                                                  ushort_t* __restrict__ whi, ushort_t* __restrict__ wlo,
                                                  const int* __restrict__ batch, int* __restrict__ gstart,
                                                  const int* __restrict__ edst, int* __restrict__ cnts) {
    __shared__ int cnt[NB];
    int b = blockIdx.x, t = threadIdx.x;
    if (b < CX_BLKS) {
        int i = b * 256 + t;                       // one uint4 (8 bf16) per thread
        if (i < N_NODES * 16) {
            float4 a = x4[2 * i], bb = x4[2 * i + 1];
            uint4 o;
            o.x = packbf2(a.x, a.y);
            o.y = packbf2(a.z, a.w);
            o.z = packbf2(bb.x, bb.y);
            o.w = packbf2(bb.z, bb.w);
            Hb4[i] = o;
        }
    } else if (b < CX_BLKS + CW_BLKS) {
        int idx = (b - CX_BLKS) * 256 + t;
        int mat = idx >> 14;
        int e = idx & 16383;
        int n = e >> 7, k = e & 127;
        int l = mat >> 1;
        const float* src = (mat & 1) ? (w2 + (size_t)l * DIM * DIM) : (w1 + (size_t)l * DIM * DIM);
        float v = src[k * DIM + n];
        ushort_t h, lw;
        bf16split(v, h, lw);
        whi[(size_t)mat * DIM * DIM + n * DIM + k] = h;
        wlo[(size_t)mat * DIM * DIM + n * DIM + k] = lw;
    } else if (b < CX_BLKS + CW_BLKS + GB_BLKS) {
        int i = (b - CX_BLKS - CW_BLKS) * 256 + t;
        if (i < N_NODES) {
            int bb = batch[i];
            if (i == 0) {
                for (int g = 0; g <= bb; ++g) gstart[g] = 0;
            } else {
                int pb = batch[i - 1];
                for (int g = pb + 1; g <= bb; ++g) gstart[g] = i;
            }
            if (i == N_NODES - 1) {
                for (int g = bb + 1; g <= N_GRAPHS; ++g) gstart[g] = N_NODES;
            }
        }
    } else {
        int blk = b - (CX_BLKS + CW_BLKS + GB_BLKS);
        for (int i = t; i < NB; i += 256) cnt[i] = 0;
        __syncthreads();
        int base = blk * EPB;
        for (int i = t; i < EPB; i += 256) atomicAdd(&cnt[edst[base + i] >> BUCKET_SHIFT], 1);
        __syncthreads();
        for (int i = t; i < NB; i += 256) cnts[i * B_CHUNK + blk] = cnt[i];
    }
}

// ---------------- scan phase 1 (over NB*B_CHUNK = 25088): block-local exclusive + block totals ----
__global__ __launch_bounds__(1024) void scan_local(const int* __restrict__ in, int* __restrict__ out,
                                                   int* __restrict__ bsum, int n) {
    __shared__ int wsum[16];
    int tid = threadIdx.x, lane = tid & 63, w = tid >> 6;
    int gi = blockIdx.x * 1024 + tid;
    int v = (gi < n) ? in[gi] : 0;
    int s = v;
    #pragma unroll
    for (int off = 1; off < 64; off <<= 1) {
        int t = __shfl_up(s, off, 64);
        if (lane >= off) s += t;
    }
    if (lane == 63) wsum[w] = s;
    __syncthreads();
    if (w == 0) {
        int ws = (lane < 16) ? wsum[lane] : 0;
        #pragma unroll
        for (int off = 1; off < 16; off <<= 1) {
            int t = __shfl_up(ws, off, 64);
            if (lane >= off) ws += t;
        }
        if (lane < 16) wsum[lane] = ws;
    }
    __syncthreads();
    int woff = (w > 0) ? wsum[w - 1] : 0;
    if (gi < n) out[gi] = woff + s - v;
    if (tid == 1023) bsum[blockIdx.x] = woff + s;
}

// ---------------- bucket CSR phase 3: place packed (dstfine<<16 | src); folds scan_add prefix --
__global__ __launch_bounds__(256) void p3_place(const int* __restrict__ src, const int* __restrict__ dst,
                                                const int* __restrict__ off, const int* __restrict__ bsum,
                                                unsigned* __restrict__ ebuf) {
    __shared__ int cur[NB];
    __shared__ int pexc[32];
    int t = threadIdx.x, blk = blockIdx.x;
    if (t < 32) {                       // exclusive prefix of the 25 scan-block totals
        int v = (t < SCAN_BLKS) ? bsum[t] : 0;
        int sI = v;
        #pragma unroll
        for (int o = 1; o < 32; o <<= 1) {
            int u = __shfl_up(sI, o, 64);
            if (t >= o) sI += u;
        }
        pexc[t] = sI - v;
    }
    __syncthreads();
    for (int i = t; i < NB; i += 256) {
        int j = i * B_CHUNK + blk;
        cur[i] = off[j] + pexc[j >> 10];
    }
    __syncthreads();
    int base = blk * EPB;
    for (int i = t; i < EPB; i += 256) {
        int d = dst[base + i];
        int b = d >> BUCKET_SHIFT;
        int pos = atomicAdd(&cur[b], 1);
        ebuf[pos] = (unsigned)src[base + i] | ((unsigned)(d & (BUCKET_SIZE - 1)) << 16);
    }
}

// ---------------- bucket CSR phase 4: per-bucket counting sort -> eoff + csr ----------------
__global__ __launch_bounds__(512) void p4_csr(const unsigned* __restrict__ ebuf, const int* __restrict__ off,
                                              const int* __restrict__ bsum,
                                              int* __restrict__ eoff, int* __restrict__ csr) {
    __shared__ int cnt[BUCKET_SIZE];
    __shared__ int wsum[8];
    __shared__ int pexc[32];
    int k = blockIdx.x, t = threadIdx.x;
    if (t < 32) {
        int v = (t < SCAN_BLKS) ? bsum[t] : 0;
        int sI = v;
        #pragma unroll
        for (int o = 1; o < 32; o <<= 1) {
            int u = __shfl_up(sI, o, 64);
            if (t >= o) sI += u;
        }
        pexc[t] = sI - v;
    }
    cnt[t] = 0;
    __syncthreads();
    int bstart = off[k * B_CHUNK] + pexc[(k * B_CHUNK) >> 10];
    int bend = (k == NB - 1) ? N_EDGES
                             : off[(k + 1) * B_CHUNK] + pexc[((k + 1) * B_CHUNK) >> 10];
    for (int i = bstart + t; i < bend; i += 512) atomicAdd(&cnt[ebuf[i] >> 16], 1);
    __syncthreads();
    int lane = t & 63, w = t >> 6;
    int v = cnt[t], s = v;
    #pragma unroll
    for (int o = 1; o < 64; o <<= 1) {
        int tt = __shfl_up(s, o, 64);
        if (lane >= o) s += tt;
    }
    if (lane == 63) wsum[w] = s;
    __syncthreads();
    if (w == 0) {
        int ws = (lane < 8) ? wsum[lane] : 0;
        #pragma unroll
        for (int o = 1; o < 8; o <<= 1) {
            int tt = __shfl_up(ws, o, 64);
            if (lane >= o) ws += tt;
        }
        if (lane < 8) wsum[lane] = ws;
    }
    __syncthreads();
    int woff = (w > 0) ? wsum[w - 1] : 0;
    int excl = woff + s - v;
    int node = k * BUCKET_SIZE + t;
    if (node < N_NODES) eoff[node] = bstart + excl;
    __syncthreads();
    cnt[t] = excl;  // reuse as cursor
    __syncthreads();
    for (int i = bstart + t; i < bend; i += 512) {
        unsigned p = ebuf[i];
        int pos = atomicAdd(&cnt[p >> 16], 1);
        csr[bstart + pos] = (int)(p & 0xffffu);
    }
    if (k == NB - 1 && t == 0) eoff[N_NODES] = N_EDGES;
}

// ---------------- GIN aggregation v4: quarter-wave edge parallelism, uint4 lanes ----------------
// One wave per node, 12.5k blocks: TLP averages out degree imbalance and hides random-row
// latency. (Round-1 lesson: fusing this into the GEMM block collapses parallelism, -16%.)
__global__ __launch_bounds__(256) void agg_bf16(const uint4* __restrict__ h4, const int* __restrict__ eoff,
                                                const int* __restrict__ csr, uint4* __restrict__ T4) {
    int wid = (blockIdx.x * 256 + threadIdx.x) >> 6;
    int lane = threadIdx.x & 63;
    int qtr = lane >> 4;
    int ql = lane & 15;
    if (wid >= N_NODES) return;
    int lo = eoff[wid], hi = eoff[wid + 1];

    float a[8];
    #pragma unroll
    for (int k = 0; k < 8; ++k) a[k] = 0.f;

    auto acc_row = [&](uint4 w) {
        a[0] += bfbits2f(w.x & 0xffffu); a[1] += bfbits2f(w.x >> 16);
        a[2] += bfbits2f(w.y & 0xffffu); a[3] += bfbits2f(w.y >> 16);
        a[4] += bfbits2f(w.z & 0xffffu); a[5] += bfbits2f(w.z >> 16);
        a[6] += bfbits2f(w.w & 0xffffu); a[7] += bfbits2f(w.w >> 16);
    };

    if (qtr == 0) acc_row(h4[(size_t)wid * 16 + ql]);  // self term

    for (int base = lo; base < hi; base += 64) {
        int nav = hi - base;
        if (nav > 64) nav = 64;
        int jv = (base + lane < hi) ? csr[base + lane] : 0;  // one coalesced index load
        int cmin = nav >> 2;
        int cmax = (nav + 3) >> 2;   // uniform loop bounds for the whole wave
        int i = 0;
        for (; i + 3 < cmin; i += 4) {  // 16 edges in flight across the wave
            int j0 = __shfl(jv, 4 * (i + 0) + qtr, 64);
            int j1 = __shfl(jv, 4 * (i + 1) + qtr, 64);
            int j2 = __shfl(jv, 4 * (i + 2) + qtr, 64);
            int j3 = __shfl(jv, 4 * (i + 3) + qtr, 64);
            uint4 w0 = h4[(size_t)j0 * 16 + ql];
            uint4 w1 = h4[(size_t)j1 * 16 + ql];
            uint4 w2 = h4[(size_t)j2 * 16 + ql];
            uint4 w3 = h4[(size_t)j3 * 16 + ql];
            acc_row(w0); acc_row(w1); acc_row(w2); acc_row(w3);
        }
        for (; i < cmin; ++i) {
            int j = __shfl(jv, 4 * i + qtr, 64);
            acc_row(h4[(size_t)j * 16 + ql]);
        }
        for (; i < cmax; ++i) {          // partial tail: shfl BEFORE the predicate
            int epos = 4 * i + qtr;
            int j = __shfl(jv, epos, 64);
            if (epos < nav) acc_row(h4[(size_t)j * 16 + ql]);
        }
    }

    #pragma unroll
    for (int k = 0; k < 8; ++k) {
        a[k] += __shfl_down(a[k], 32, 64);
        a[k] += __shfl_down(a[k], 16, 64);
    }
    if (qtr == 0) {
        uint4 o;
        o.x = packbf2(a[0], a[1]);
        o.y = packbf2(a[2], a[3]);
        o.z = packbf2(a[4], a[5]);
        o.w = packbf2(a[6], a[7]);
        T4[(size_t)wid * 16 + ql] = o;
    }
}

// ---------------- fused layer GEMM v2: 256-row tile, 512 threads (8 waves), 96 KB LDS --------
// Zb = relu(relu(T@W1+b1)@W2+b2); Z1 round-trips through As in LDS. Halves W staging +
// barrier count per row vs the 128-row version; grid 196 <= 256 CUs -> single round.
__global__ __launch_bounds__(512) void mm_layer(const ushort_t* __restrict__ A,
                                                const ushort_t* __restrict__ W1h, const ushort_t* __restrict__ W1l,
                                                const ushort_t* __restrict__ W2h, const ushort_t* __restrict__ W2l,
                                                const float* __restrict__ b1, const float* __restrict__ b2,
                                                ushort_t* __restrict__ Zb) {
    __shared__ ushort_t As[256 * 128];   // 64 KB
    __shared__ ushort_t Ws[128 * 128];   // 32 KB
    int tid = threadIdx.x;
    int row0 = blockIdx.x * 256;
    int wave = tid >> 6, lane = tid & 63;   // wave 0..7, each owns 32 rows
    int q = lane >> 4, mn = lane & 15;

    f32x4 acc[2][8];
    #pragma unroll
    for (int t = 0; t < 2; ++t)
        #pragma unroll
        for (int n = 0; n < 8; ++n) acc[t][n] = (f32x4)(0.f);

    // stage A: 256 rows x 16 uint4-chunks = 4096 chunks, 512 thr -> 8 iters
    #pragma unroll
    for (int i = 0; i < 8; ++i) {
        int c = tid + i * 512;
        int r = c >> 4, c8 = c & 15;
        uint4 v = make_uint4(0u, 0u, 0u, 0u);
        int gr = row0 + r;
        if (gr < N_NODES) v = *(const uint4*)(A + (size_t)gr * DIM + c8 * 8);
        *(uint4*)(&As[r * 128 + (c8 ^ (r & 7)) * 8]) = v;
    }
    auto stageW = [&](const ushort_t* src) {   // 2048 chunks, 512 thr -> 4 iters
        #pragma unroll
        for (int i = 0; i < 4; ++i) {
            int c = tid + i * 512;
            int r = c >> 4, c8 = c & 15;
            uint4 v = *(const uint4*)(src + r * DIM + c8 * 8);
            *(uint4*)(&Ws[r * 128 + (c8 ^ (r & 7)) * 8]) = v;
        }
    };
    auto compute = [&]() {
        #pragma unroll
        for (int ks = 0; ks < 4; ++ks) {
            int m0 = wave * 32 + mn;
            int m1 = m0 + 16;
            frag8 a0 = *(const frag8*)&As[m0 * 128 + (((ks * 4 + q) ^ (m0 & 7)) * 8)];
            frag8 a1 = *(const frag8*)&As[m1 * 128 + (((ks * 4 + q) ^ (m1 & 7)) * 8)];
            #pragma unroll
            for (int n = 0; n < 8; ++n) {
                int nr = n * 16 + mn;
                frag8 b = *(const frag8*)&Ws[nr * 128 + (((ks * 4 + q) ^ (nr & 7)) * 8)];
                acc[0][n] = __builtin_amdgcn_mfma_f32_16x16x32_bf16(a0, b, acc[0][n], 0, 0, 0);
                acc[1][n] = __builtin_amdgcn_mfma_f32_16x16x32_bf16(a1, b, acc[1][n], 0, 0, 0);
            }
        }
    };

    // ---- GEMM 1: Z1 = relu(A@W1 + b1) ----
    stageW(W1h);
    __syncthreads(); compute(); __syncthreads();
    stageW(W1l);
    __syncthreads(); compute(); __syncthreads();

    // epilogue 1: write bf16 Z1 back into As (swizzled), reset acc
    int mloc = wave * 32;
    #pragma unroll
    for (int t = 0; t < 2; ++t) {
        #pragma unroll
        for (int n = 0; n < 8; ++n) {
            int col = n * 16 + mn;
            float bv = b1[col];
            #pragma unroll
            for (int r = 0; r < 4; ++r) {
                int rloc = mloc + t * 16 + q * 4 + r;
                float v = fmaxf(acc[t][n][r] + bv, 0.f);
                As[rloc * 128 + ((col >> 3) ^ (rloc & 7)) * 8 + (col & 7)] = bf16rne(v);
                acc[t][n][r] = 0.f;
            }
        }
    }
    __syncthreads();
    // ---- GEMM 2: Z = relu(Z1@W2 + b2) ----
    stageW(W2h);
    __syncthreads(); compute(); __syncthreads();
    stageW(W2l);
    __syncthreads(); compute();

    // epilogue 2: bf16 streaming store
    #pragma unroll
    for (int t = 0; t < 2; ++t) {
        #pragma unroll
        for (int n = 0; n < 8; ++n) {
            int col = n * 16 + mn;
            float bv = b2[col];
            #pragma unroll
            for (int r = 0; r < 4; ++r) {
                int grow = row0 + mloc + t * 16 + q * 4 + r;
                if (grow < N_NODES)
                    Zb[(size_t)grow * DIM + col] = bf16rne(fmaxf(acc[t][n][r] + bv, 0.f));
            }
        }
    }
}

// ---------------- fused GraphNorm (non-last), DIM-SPLIT: 2 blocks/graph, uint2 lanes ----------
__global__ __launch_bounds__(1024) void gn_fused(const unsigned* __restrict__ Zb, const int* __restrict__ gstart,
                                                 const float* __restrict__ scale, const float* __restrict__ weight,
                                                 const float* __restrict__ bias,
                                                 unsigned* __restrict__ Hb) {
    __shared__ f32x4 sh1[1024], sh2[1024];
    __shared__ float sa[64], sb[64];
    int g = blockIdx.x >> 1, half = blockIdx.x & 1;
    int t = threadIdx.x;
    int uld = t & 15, rg = t >> 4;           // 16 uint2-cols x 64 row-groups
    int s = gstart[g], e = gstart[g + 1];
    const unsigned* zp = Zb + half * 32 + uld * 2;
    f32x4 s1 = (f32x4)(0.f), s2 = (f32x4)(0.f);
    for (int n = s + rg; n < e; n += 64) {
        uint2 zz = *(const uint2*)(zp + (size_t)n * 64);
        f32x4 z;
        z[0] = bfbits2f(zz.x & 0xffffu); z[1] = bfbits2f(zz.x >> 16);
        z[2] = bfbits2f(zz.y & 0xffffu); z[3] = bfbits2f(zz.y >> 16);
        s1 += z;
        s2 += z * z;
    }
    sh1[t] = s1;
    sh2[t] = s2;
    __syncthreads();
    int dbase = half * 64 + uld * 4;
    if (rg == 0) {
        #pragma unroll 8
        for (int k = 1; k < 64; ++k) { s1 += sh1[uld + 16 * k]; s2 += sh2[uld + 16 * k]; }
        int cnt = e - s;
        float cf = (float)(cnt > 0 ? cnt : 1);
        #pragma unroll
        for (int j = 0; j < 4; ++j) {
            float m = s1[j] / cf, ez = s2[j] / cf;
            float sc = scale[dbase + j];
            float var = fmaxf(ez - (2.0f - sc) * sc * m * m, 0.f);
            sa[uld * 4 + j] = m * sc;
            sb[uld * 4 + j] = weight[dbase + j] / sqrtf(var + GN_EPS);
        }
    }
    __syncthreads();
    float as0 = sa[uld * 4], as1 = sa[uld * 4 + 1], as2 = sa[uld * 4 + 2], as3 = sa[uld * 4 + 3];
    float bm0 = sb[uld * 4], bm1 = sb[uld * 4 + 1], bm2 = sb[uld * 4 + 2], bm3 = sb[uld * 4 + 3];
    float bi0 = bias[dbase], bi1 = bias[dbase + 1], bi2 = bias[dbase + 2], bi3 = bias[dbase + 3];
    unsigned* hp = Hb + half * 32 + uld * 2;
    for (int n = s + rg; n < e; n += 64) {
        uint2 zz = *(const uint2*)(zp + (size_t)n * 64);
        float z0 = bfbits2f(zz.x & 0xffffu), z1 = bfbits2f(zz.x >> 16);
        float z2 = bfbits2f(zz.y & 0xffffu), z3 = bfbits2f(zz.y >> 16);
        float o0 = fmaxf((z0 - as0) * bm0 + bi0, 0.f);
        float o1 = fmaxf((z1 - as1) * bm1 + bi1, 0.f);
        float o2 = fmaxf((z2 - as2) * bm2 + bi2, 0.f);
        float o3 = fmaxf((z3 - as3) * bm3 + bi3, 0.f);
        uint2 o;
        o.x = packbf2(o0, o1);
        o.y = packbf2(o2, o3);
        *(uint2*)(hp + (size_t)n * 64) = o;
    }
}

// ---------------- last layer: GraphNorm + relu + readout + final MLP + log_softmax ----------
__global__ __launch_bounds__(1024) void gn_last(const unsigned* __restrict__ Zb, const int* __restrict__ gstart,
                                                const float* __restrict__ scale, const float* __restrict__ weight,
                                                const float* __restrict__ bias,
                                                const float* __restrict__ fw1, const float* __restrict__ fb1,
                                                const float* __restrict__ fw2, const float* __restrict__ fb2,
                                                const float* __restrict__ fw3, const float* __restrict__ fb3,
                                                float* __restrict__ out) {
    __shared__ f32x4 sh1[1024], sh2[1024];
    __shared__ float sa[128], sb[128];
    __shared__ float v0[128], v1[128], v2[128], lg[10];
    int g = blockIdx.x;
    int t = threadIdx.x;
    int du = t & 31, rg = t >> 5;            // 32 uint2-cols x 32 row-groups
    int s = gstart[g], e = gstart[g + 1];
    const unsigned* zp = Zb + du * 2;
    f32x4 s1 = (f32x4)(0.f), s2 = (f32x4)(0.f);
    for (int n = s + rg; n < e; n += 32) {
        uint2 zz = *(const uint2*)(zp + (size_t)n * 64);
        f32x4 z;
        z[0] = bfbits2f(zz.x & 0xffffu); z[1] = bfbits2f(zz.x >> 16);
        z[2] = bfbits2f(zz.y & 0xffffu); z[3] = bfbits2f(zz.y >> 16);
        s1 += z;
        s2 += z * z;
    }
    sh1[t] = s1;
    sh2[t] = s2;
    __syncthreads();
    int dbase = du * 4;
    if (rg == 0) {
        #pragma unroll 8
        for (int k = 1; k < 32; ++k) { s1 += sh1[du + 32 * k]; s2 += sh2[du + 32 * k]; }
        int cnt = e - s;
        float cf = (float)(cnt > 0 ? cnt : 1);
        #pragma unroll
        for (int j = 0; j < 4; ++j) {
            float m = s1[j] / cf, ez = s2[j] / cf;
            float sc = scale[dbase + j];
            float var = fmaxf(ez - (2.0f - sc) * sc * m * m, 0.f);
            sa[dbase + j] = m * sc;
            sb[dbase + j] = weight[dbase + j] / sqrtf(var + GN_EPS);
        }
    }
    __syncthreads();
    float as_[4], bm_[4], bi_[4];
    #pragma unroll
    for (int j = 0; j < 4; ++j) {
        as_[j] = sa[dbase + j];
        bm_[j] = sb[dbase + j];
        bi_[j] = bias[dbase + j];
    }
    f32x4 rsum = (f32x4)(0.f);
    for (int n = s + rg; n < e; n += 32) {
        uint2 zz = *(const uint2*)(zp + (size_t)n * 64);
        float z0 = bfbits2f(zz.x & 0xffffu), z1 = bfbits2f(zz.x >> 16);
        float z2 = bfbits2f(zz.y & 0xffffu), z3 = bfbits2f(zz.y >> 16);
        rsum[0] += fmaxf((z0 - as_[0]) * bm_[0] + bi_[0], 0.f);
        rsum[1] += fmaxf((z1 - as_[1]) * bm_[1] + bi_[1], 0.f);
        rsum[2] += fmaxf((z2 - as_[2]) * bm_[2] + bi_[2], 0.f);
        rsum[3] += fmaxf((z3 - as_[3]) * bm_[3] + bi_[3], 0.f);
    }
    __syncthreads();
    sh1[t] = rsum;
    __syncthreads();
    if (rg == 0) {
        #pragma unroll 8
        for (int k = 1; k < 32; ++k) rsum += sh1[du + 32 * k];
        #pragma unroll
        for (int j = 0; j < 4; ++j) v0[dbase + j] = rsum[j];
    }
    __syncthreads();
    if (t < 128) {
        float acc = fb1[t];
        for (int d = 0; d < 128; ++d) acc += v0[d] * fw1[d * 128 + t];
        v1[t] = fmaxf(acc, 0.f);
    }
    __syncthreads();
    if (t < 128) {
        float acc = fb2[t];
        for (int d = 0; d < 128; ++d) acc += v1[d] * fw2[d * 128 + t];
        v2[t] = fmaxf(acc, 0.f);
    }
    __syncthreads();
    if (t < 10) {
        float acc = fb3[t];
        for (int d = 0; d < 128; ++d) acc += v2[d] * fw3[d * 10 + t];
        lg[t] = acc;
    }
    __syncthreads();
    if (t < 10) {
        float m = -1e30f;
        for (int c = 0; c < 10; ++c) m = fmaxf(m, lg[c]);
        float ssum = 0.f;
        for (int c = 0; c < 10; ++c) ssum += expf(lg[c] - m);
        out[g * 10 + t] = lg[t] - m - logf(ssum);
    }
}

extern "C" void kernel_launch(void* const* d_in, const int* in_sizes, int n_in,
                              void* d_out, int out_size, void* d_ws, size_t ws_size,
                              hipStream_t stream) {
    const float* x      = (const float*)d_in[0];
    const float* gin_w1 = (const float*)d_in[1];
    const float* gin_b1 = (const float*)d_in[2];
    const float* gin_w2 = (const float*)d_in[3];
    const float* gin_b2 = (const float*)d_in[4];
    const float* gn_w   = (const float*)d_in[5];
    const float* gn_b   = (const float*)d_in[6];
    const float* gn_s   = (const float*)d_in[7];
    const float* fw1    = (const float*)d_in[8];
    const float* fb1    = (const float*)d_in[9];
    const float* fw2    = (const float*)d_in[10];
    const float* fb2    = (const float*)d_in[11];
    const float* fw3    = (const float*)d_in[12];
    const float* fb3    = (const float*)d_in[13];
    const int*   eidx   = (const int*)d_in[14];
    const int*   batch  = (const int*)d_in[15];
    float* out = (float*)d_out;

    const int* esrc = eidx;
    const int* edst = eidx + N_EDGES;

    auto align_up = [](size_t v) { return (v + 255) & ~(size_t)255; };
    char* p = (char*)d_ws;
    unsigned* Hb = (unsigned*)p;   p += align_up((size_t)N_NODES * DIM * 2);
    unsigned* Tb = (unsigned*)p;   p += align_up((size_t)N_NODES * DIM * 2);
    unsigned* Zb = (unsigned*)p;   p += align_up((size_t)N_NODES * DIM * 2);
    ushort_t* WThi = (ushort_t*)p; p += align_up((size_t)8 * DIM * DIM * 2);
    ushort_t* WTlo = (ushort_t*)p; p += align_up((size_t)8 * DIM * DIM * 2);
    int* gstart = (int*)p;         p += align_up((N_GRAPHS + 1) * 4);
    int* cnts = (int*)p;           p += align_up((size_t)NB * B_CHUNK * 4);
    int* off = (int*)p;            p += align_up(((size_t)NB * B_CHUNK + 1) * 4);
    int* bsum = (int*)p;           p += align_up(64 * 4);
    unsigned* ebuf = (unsigned*)p; p += align_up((size_t)N_EDGES * 4);
    int* eoff = (int*)p;           p += align_up((N_NODES + 1) * 4);
    int* csr = (int*)p;            p += align_up((size_t)N_EDGES * 4);

    const int SCAN_N = NB * B_CHUNK;                      // 25088
    setup_misc<<<SETUP_BLKS, 256, 0, stream>>>((const float4*)x, (uint4*)Hb, gin_w1, gin_w2,
                                               WThi, WTlo, batch, gstart, edst, cnts);
    scan_local<<<SCAN_BLKS, 1024, 0, stream>>>(cnts, off, bsum, SCAN_N);
    p3_place<<<B_CHUNK, 256, 0, stream>>>(esrc, edst, off, bsum, ebuf);
    p4_csr<<<NB, 512, 0, stream>>>(ebuf, off, bsum, eoff, csr);

    const int mm_grid = (N_NODES + 255) / 256;  // 196 blocks <= 256 CUs
    for (int l = 0; l < N_LAYERS; ++l) {
        agg_bf16<<<(N_NODES + 3) / 4, 256, 0, stream>>>((const uint4*)Hb, eoff, csr, (uint4*)Tb);
        mm_layer<<<mm_grid, 512, 0, stream>>>((const ushort_t*)Tb,
            WThi + (size_t)(2 * l) * DIM * DIM, WTlo + (size_t)(2 * l) * DIM * DIM,
            WThi + (size_t)(2 * l + 1) * DIM * DIM, WTlo + (size_t)(2 * l + 1) * DIM * DIM,
            gin_b1 + l * DIM, gin_b2 + l * DIM, (ushort_t*)Zb);
        if (l == N_LAYERS - 1)
            gn_last<<<N_GRAPHS, 1024, 0, stream>>>(Zb, gstart, gn_s + l * DIM,
                gn_w + l * DIM, gn_b + l * DIM, fw1, fb1, fw2, fb2, fw3, fb3, out);
        else
            gn_fused<<<N_GRAPHS * 2, 1024, 0, stream>>>(Zb, gstart, gn_s + l * DIM,
                gn_w + l * DIM, gn_b + l * DIM, Hb);
    }
}

// Round 5
// 380.011 us; speedup vs baseline: 1.1506x; 1.0025x over previous
//
#include <hip/hip_runtime.h>
#include <cstddef>

#define N_NODES 50000
#define N_EDGES 800000
#define N_GRAPHS 128
#define DIM 128
#define N_LAYERS 4
#define GN_EPS 1e-5f

// bucket-sort params
#define B_CHUNK 256        // chunk blocks
#define EPB 3125           // edges per chunk (256*3125 = 800000 exactly)
#define BUCKET_SHIFT 9
#define BUCKET_SIZE 512
#define NB 98              // ceil(50000/512)
#define SCAN_BLKS 25       // ceil(NB*B_CHUNK / 1024)

// setup_misc grid partition
#define CX_BLKS 3125       // convert_x vectorized: 50000*16 uint4 / 256
#define CW_BLKS 512        // convert_w: 8*128*128 / 256
#define GB_BLKS 196        // graph_bounds: ceil(50000/256)
#define SETUP_BLKS (CX_BLKS + CW_BLKS + GB_BLKS + B_CHUNK)

typedef unsigned short ushort_t;
typedef __attribute__((ext_vector_type(8))) short frag8;
typedef __attribute__((ext_vector_type(4))) float f32x4;
typedef __attribute__((ext_vector_type(2))) float f32x2;

__device__ inline float bfbits2f(unsigned hi16) { return __uint_as_float(hi16 << 16); }
__device__ inline ushort_t bf16rne(float v) {
    unsigned u = __float_as_uint(v);
    unsigned r = u + 0x7fff + ((u >> 16) & 1);
    return (ushort_t)(r >> 16);
}
__device__ inline unsigned packbf2(float a, float b) {
    return (unsigned)bf16rne(a) | ((unsigned)bf16rne(b) << 16);
}
__device__ inline void bf16split(float v, ushort_t& h, ushort_t& l) {
    ushort_t hi = bf16rne(v);
    float fh = __uint_as_float(((unsigned)hi) << 16);
    l = bf16rne(v - fh);
    h = hi;
}
// unpack one uint (2 bf16) into a packed float2 {lo, hi} -> enables v_pk_add_f32 accumulate
__device__ inline f32x2 bf2pair(unsigned w) {
    union { unsigned u[2]; f32x2 f; } c;
    c.u[0] = w << 16;
    c.u[1] = w & 0xffff0000u;
    return c.f;
}

// ---------------- merged independent setup: convert_x | convert_w | graph_bounds | p1_count ----
__global__ __launch_bounds__(256) void setup_misc(const float4* __restrict__ x4, uint4* __restrict__ Hb4,
                                                  const float* __restrict__ w1, const float* __restrict__ w2,
                                                  ushort_t* __restrict__ whi, ushort_t* __restrict__ wlo,
                                                  const int* __restrict__ batch, int* __restrict__ gstart,
                                                  const int* __restrict__ edst, int* __restrict__ cnts) {
    __shared__ int cnt[NB];
    int b = blockIdx.x, t = threadIdx.x;
    if (b < CX_BLKS) {
        int i = b * 256 + t;                       // one uint4 (8 bf16) per thread
        if (i < N_NODES * 16) {
            float4 a = x4[2 * i], bb = x4[2 * i + 1];
            uint4 o;
            o.x = packbf2(a.x, a.y);
            o.y = packbf2(a.z, a.w);
            o.z = packbf2(bb.x, bb.y);
            o.w = packbf2(bb.z, bb.w);
            Hb4[i] = o;
        }
    } else if (b < CX_BLKS + CW_BLKS) {
        int idx = (b - CX_BLKS) * 256 + t;
        int mat = idx >> 14;
        int e = idx & 16383;
        int n = e >> 7, k = e & 127;
        int l = mat >> 1;
        const float* src = (mat & 1) ? (w2 + (size_t)l * DIM * DIM) : (w1 + (size_t)l * DIM * DIM);
        float v = src[k * DIM + n];
        ushort_t h, lw;
        bf16split(v, h, lw);
        whi[(size_t)mat * DIM * DIM + n * DIM + k] = h;
        wlo[(size_t)mat * DIM * DIM + n * DIM + k] = lw;
    } else if (b < CX_BLKS + CW_BLKS + GB_BLKS) {
        int i = (b - CX_BLKS - CW_BLKS) * 256 + t;
        if (i < N_NODES) {
            int bb = batch[i];
            if (i == 0) {
                for (int g = 0; g <= bb; ++g) gstart[g] = 0;
            } else {
                int pb = batch[i - 1];
                for (int g = pb + 1; g <= bb; ++g) gstart[g] = i;
            }
            if (i == N_NODES - 1) {
                for (int g = bb + 1; g <= N_GRAPHS; ++g) gstart[g] = N_NODES;
            }
        }
    } else {
        int blk = b - (CX_BLKS + CW_BLKS + GB_BLKS);
        for (int i = t; i < NB; i += 256) cnt[i] = 0;
        __syncthreads();
        int base = blk * EPB;
        for (int i = t; i < EPB; i += 256) atomicAdd(&cnt[edst[base + i] >> BUCKET_SHIFT], 1);
        __syncthreads();
        for (int i = t; i < NB; i += 256) cnts[i * B_CHUNK + blk] = cnt[i];
    }
}

// ---------------- scan phase 1 (over NB*B_CHUNK = 25088): block-local exclusive + block totals ----
__global__ __launch_bounds__(1024) void scan_local(const int* __restrict__ in, int* __restrict__ out,
                                                   int* __restrict__ bsum, int n) {
    __shared__ int wsum[16];
    int tid = threadIdx.x, lane = tid & 63, w = tid >> 6;
    int gi = blockIdx.x * 1024 + tid;
    int v = (gi < n) ? in[gi] : 0;
    int s = v;
    #pragma unroll
    for (int off = 1; off < 64; off <<= 1) {
        int t = __shfl_up(s, off, 64);
        if (lane >= off) s += t;
    }
    if (lane == 63) wsum[w] = s;
    __syncthreads();
    if (w == 0) {
        int ws = (lane < 16) ? wsum[lane] : 0;
        #pragma unroll
        for (int off = 1; off < 16; off <<= 1) {
            int t = __shfl_up(ws, off, 64);
            if (lane >= off) ws += t;
        }
        if (lane < 16) wsum[lane] = ws;
    }
    __syncthreads();
    int woff = (w > 0) ? wsum[w - 1] : 0;
    if (gi < n) out[gi] = woff + s - v;
    if (tid == 1023) bsum[blockIdx.x] = woff + s;
}

// ---------------- bucket CSR phase 3: place packed (dstfine<<16 | src); folds scan_add prefix --
__global__ __launch_bounds__(256) void p3_place(const int* __restrict__ src, const int* __restrict__ dst,
                                                const int* __restrict__ off, const int* __restrict__ bsum,
                                                unsigned* __restrict__ ebuf) {
    __shared__ int cur[NB];
    __shared__ int pexc[32];
    int t = threadIdx.x, blk = blockIdx.x;
    if (t < 32) {                       // exclusive prefix of the 25 scan-block totals
        int v = (t < SCAN_BLKS) ? bsum[t] : 0;
        int sI = v;
        #pragma unroll
        for (int o = 1; o < 32; o <<= 1) {
            int u = __shfl_up(sI, o, 64);
            if (t >= o) sI += u;
        }
        pexc[t] = sI - v;
    }
    __syncthreads();
    for (int i = t; i < NB; i += 256) {
        int j = i * B_CHUNK + blk;
        cur[i] = off[j] + pexc[j >> 10];
    }
    __syncthreads();
    int base = blk * EPB;
    for (int i = t; i < EPB; i += 256) {
        int d = dst[base + i];
        int b = d >> BUCKET_SHIFT;
        int pos = atomicAdd(&cur[b], 1);
        ebuf[pos] = (unsigned)src[base + i] | ((unsigned)(d & (BUCKET_SIZE - 1)) << 16);
    }
}

// ---------------- bucket CSR phase 4: per-bucket counting sort -> eoff + csr ----------------
__global__ __launch_bounds__(512) void p4_csr(const unsigned* __restrict__ ebuf, const int* __restrict__ off,
                                              const int* __restrict__ bsum,
                                              int* __restrict__ eoff, int* __restrict__ csr) {
    __shared__ int cnt[BUCKET_SIZE];
    __shared__ int wsum[8];
    __shared__ int pexc[32];
    int k = blockIdx.x, t = threadIdx.x;
    if (t < 32) {
        int v = (t < SCAN_BLKS) ? bsum[t] : 0;
        int sI = v;
        #pragma unroll
        for (int o = 1; o < 32; o <<= 1) {
            int u = __shfl_up(sI, o, 64);
            if (t >= o) sI += u;
        }
        pexc[t] = sI - v;
    }
    cnt[t] = 0;
    __syncthreads();
    int bstart = off[k * B_CHUNK] + pexc[(k * B_CHUNK) >> 10];
    int bend = (k == NB - 1) ? N_EDGES
                             : off[(k + 1) * B_CHUNK] + pexc[((k + 1) * B_CHUNK) >> 10];
    for (int i = bstart + t; i < bend; i += 512) atomicAdd(&cnt[ebuf[i] >> 16], 1);
    __syncthreads();
    int lane = t & 63, w = t >> 6;
    int v = cnt[t], s = v;
    #pragma unroll
    for (int o = 1; o < 64; o <<= 1) {
        int tt = __shfl_up(s, o, 64);
        if (lane >= o) s += tt;
    }
    if (lane == 63) wsum[w] = s;
    __syncthreads();
    if (w == 0) {
        int ws = (lane < 8) ? wsum[lane] : 0;
        #pragma unroll
        for (int o = 1; o < 8; o <<= 1) {
            int tt = __shfl_up(ws, o, 64);
            if (lane >= o) ws += tt;
        }
        if (lane < 8) wsum[lane] = ws;
    }
    __syncthreads();
    int woff = (w > 0) ? wsum[w - 1] : 0;
    int excl = woff + s - v;
    int node = k * BUCKET_SIZE + t;
    if (node < N_NODES) eoff[node] = bstart + excl;
    __syncthreads();
    cnt[t] = excl;  // reuse as cursor
    __syncthreads();
    for (int i = bstart + t; i < bend; i += 512) {
        unsigned p = ebuf[i];
        int pos = atomicAdd(&cnt[p >> 16], 1);
        csr[bstart + pos] = (int)(p & 0xffffu);
    }
    if (k == NB - 1 && t == 0) eoff[N_NODES] = N_EDGES;
}

// ---------------- GIN aggregation v5: quarter-wave edge parallelism, packed f32 accumulate ----
// One wave per node, 12.5k blocks (round-1 lesson: keep max TLP). v_pk_add_f32 via f32x2
// accumulators cuts per-row VALU 16->12 insts/lane; per-element add order unchanged
// (bit-identical to v4).
__global__ __launch_bounds__(256) void agg_bf16(const uint4* __restrict__ h4, const int* __restrict__ eoff,
                                                const int* __restrict__ csr, uint4* __restrict__ T4) {
    int wid = (blockIdx.x * 256 + threadIdx.x) >> 6;
    int lane = threadIdx.x & 63;
    int qtr = lane >> 4;
    int ql = lane & 15;
    if (wid >= N_NODES) return;
    int lo = eoff[wid], hi = eoff[wid + 1];

    f32x2 a[4];
    #pragma unroll
    for (int k = 0; k < 4; ++k) a[k] = (f32x2)(0.f);

    auto acc_row = [&](uint4 w) {
        a[0] += bf2pair(w.x);
        a[1] += bf2pair(w.y);
        a[2] += bf2pair(w.z);
        a[3] += bf2pair(w.w);
    };

    if (qtr == 0) acc_row(h4[(size_t)wid * 16 + ql]);  // self term

    for (int base = lo; base < hi; base += 64) {
        int nav = hi - base;
        if (nav > 64) nav = 64;
        int jv = (base + lane < hi) ? csr[base + lane] : 0;  // one coalesced index load
        int cmin = nav >> 2;
        int cmax = (nav + 3) >> 2;   // uniform loop bounds for the whole wave
        int i = 0;
        for (; i + 3 < cmin; i += 4) {  // 16 edges in flight across the wave
            int j0 = __shfl(jv, 4 * (i + 0) + qtr, 64);
            int j1 = __shfl(jv, 4 * (i + 1) + qtr, 64);
            int j2 = __shfl(jv, 4 * (i + 2) + qtr, 64);
            int j3 = __shfl(jv, 4 * (i + 3) + qtr, 64);
            uint4 w0 = h4[(size_t)j0 * 16 + ql];
            uint4 w1 = h4[(size_t)j1 * 16 + ql];
            uint4 w2 = h4[(size_t)j2 * 16 + ql];
            uint4 w3 = h4[(size_t)j3 * 16 + ql];
            acc_row(w0); acc_row(w1); acc_row(w2); acc_row(w3);
        }
        for (; i < cmin; ++i) {
            int j = __shfl(jv, 4 * i + qtr, 64);
            acc_row(h4[(size_t)j * 16 + ql]);
        }
        for (; i < cmax; ++i) {          // partial tail: shfl BEFORE the predicate
            int epos = 4 * i + qtr;
            int j = __shfl(jv, epos, 64);
            if (epos < nav) acc_row(h4[(size_t)j * 16 + ql]);
        }
    }

    float f[8] = {a[0].x, a[0].y, a[1].x, a[1].y, a[2].x, a[2].y, a[3].x, a[3].y};
    #pragma unroll
    for (int k = 0; k < 8; ++k) {
        f[k] += __shfl_down(f[k], 32, 64);
        f[k] += __shfl_down(f[k], 16, 64);
    }
    if (qtr == 0) {
        uint4 o;
        o.x = packbf2(f[0], f[1]);
        o.y = packbf2(f[2], f[3]);
        o.z = packbf2(f[4], f[5]);
        o.w = packbf2(f[6], f[7]);
        T4[(size_t)wid * 16 + ql] = o;
    }
}

// ---------------- fused layer GEMM v3: 256-row tile, 512 threads, Ws double-buffer, 128 KB LDS
// Zb = relu(relu(T@W1+b1)@W2+b2); Z1 round-trips through As in LDS. The next weight half is
// staged into the other Ws buffer concurrently with compute -> staging hides under MFMA and
// barrier count drops 7->5. Still 1 block/CU (128 KB of 160 KB).
__global__ __launch_bounds__(512) void mm_layer(const ushort_t* __restrict__ A,
                                                const ushort_t* __restrict__ W1h, const ushort_t* __restrict__ W1l,
                                                const ushort_t* __restrict__ W2h, const ushort_t* __restrict__ W2l,
                                                const float* __restrict__ b1, const float* __restrict__ b2,
                                                ushort_t* __restrict__ Zb) {
    __shared__ ushort_t As[256 * 128];      // 64 KB
    __shared__ ushort_t Ws[2][128 * 128];   // 64 KB
    int tid = threadIdx.x;
    int row0 = blockIdx.x * 256;
    int wave = tid >> 6, lane = tid & 63;   // wave 0..7, each owns 32 rows
    int q = lane >> 4, mn = lane & 15;

    f32x4 acc[2][8];
    #pragma unroll
    for (int t = 0; t < 2; ++t)
        #pragma unroll
        for (int n = 0; n < 8; ++n) acc[t][n] = (f32x4)(0.f);

    // stage A: 256 rows x 16 uint4-chunks = 4096 chunks, 512 thr -> 8 iters
    #pragma unroll
    for (int i = 0; i < 8; ++i) {
        int c = tid + i * 512;
        int r = c >> 4, c8 = c & 15;
        uint4 v = make_uint4(0u, 0u, 0u, 0u);
        int gr = row0 + r;
        if (gr < N_NODES) v = *(const uint4*)(A + (size_t)gr * DIM + c8 * 8);
        *(uint4*)(&As[r * 128 + (c8 ^ (r & 7)) * 8]) = v;
    }
    auto stageW = [&](int buf, const ushort_t* src) {   // 2048 chunks, 512 thr -> 4 iters
        #pragma unroll
        for (int i = 0; i < 4; ++i) {
            int c = tid + i * 512;
            int r = c >> 4, c8 = c & 15;
            uint4 v = *(const uint4*)(src + r * DIM + c8 * 8);
            *(uint4*)(&Ws[buf][r * 128 + (c8 ^ (r & 7)) * 8]) = v;
        }
    };
    auto compute = [&](int buf) {
        #pragma unroll
        for (int ks = 0; ks < 4; ++ks) {
            int m0 = wave * 32 + mn;
            int m1 = m0 + 16;
            frag8 a0 = *(const frag8*)&As[m0 * 128 + (((ks * 4 + q) ^ (m0 & 7)) * 8)];
            frag8 a1 = *(const frag8*)&As[m1 * 128 + (((ks * 4 + q) ^ (m1 & 7)) * 8)];
            #pragma unroll
            for (int n = 0; n < 8; ++n) {
                int nr = n * 16 + mn;
                frag8 b = *(const frag8*)&Ws[buf][nr * 128 + (((ks * 4 + q) ^ (nr & 7)) * 8)];
                acc[0][n] = __builtin_amdgcn_mfma_f32_16x16x32_bf16(a0, b, acc[0][n], 0, 0, 0);
                acc[1][n] = __builtin_amdgcn_mfma_f32_16x16x32_bf16(a1, b, acc[1][n], 0, 0, 0);
            }
        }
    };

    // ---- GEMM 1: Z1 = relu(A@W1 + b1), W1l staged under W1h compute ----
    stageW(0, W1h);
    __syncthreads();                 // As + Ws0 ready
    stageW(1, W1l);
    compute(0);
    __syncthreads();                 // Ws1 ready
    compute(1);
    __syncthreads();                 // all As reads done

    // epilogue 1: write bf16 Z1 back into As (swizzled), reset acc; stage W2h alongside
    int mloc = wave * 32;
    #pragma unroll
    for (int t = 0; t < 2; ++t) {
        #pragma unroll
        for (int n = 0; n < 8; ++n) {
            int col = n * 16 + mn;
            float bv = b1[col];
            #pragma unroll
            for (int r = 0; r < 4; ++r) {
                int rloc = mloc + t * 16 + q * 4 + r;
                float v = fmaxf(acc[t][n][r] + bv, 0.f);
                As[rloc * 128 + ((col >> 3) ^ (rloc & 7)) * 8 + (col & 7)] = bf16rne(v);
                acc[t][n][r] = 0.f;
            }
        }
    }
    stageW(0, W2h);
    __syncthreads();                 // As(Z1) + Ws0(W2h) ready

    // ---- GEMM 2: Z = relu(Z1@W2 + b2), W2l staged under W2h compute ----
    stageW(1, W2l);
    compute(0);
    __syncthreads();                 // Ws1 ready
    compute(1);

    // epilogue 2: bf16 streaming store
    #pragma unroll
    for (int t = 0; t < 2; ++t) {
        #pragma unroll
        for (int n = 0; n < 8; ++n) {
            int col = n * 16 + mn;
            float bv = b2[col];
            #pragma unroll
            for (int r = 0; r < 4; ++r) {
                int grow = row0 + mloc + t * 16 + q * 4 + r;
                if (grow < N_NODES)
                    Zb[(size_t)grow * DIM + col] = bf16rne(fmaxf(acc[t][n][r] + bv, 0.f));
            }
        }
    }
}

// ---------------- fused GraphNorm (non-last), DIM-SPLIT: 2 blocks/graph, uint2 lanes ----------
__global__ __launch_bounds__(1024) void gn_fused(const unsigned* __restrict__ Zb, const int* __restrict__ gstart,
                                                 const float* __restrict__ scale, const float* __restrict__ weight,
                                                 const float* __restrict__ bias,
                                                 unsigned* __restrict__ Hb) {
    __shared__ f32x4 sh1[1024], sh2[1024];
    __shared__ float sa[64], sb[64];
    int g = blockIdx.x >> 1, half = blockIdx.x & 1;
    int t = threadIdx.x;
    int uld = t & 15, rg = t >> 4;           // 16 uint2-cols x 64 row-groups
    int s = gstart[g], e = gstart[g + 1];
    const unsigned* zp = Zb + half * 32 + uld * 2;
    f32x4 s1 = (f32x4)(0.f), s2 = (f32x4)(0.f);
    for (int n = s + rg; n < e; n += 64) {
        uint2 zz = *(const uint2*)(zp + (size_t)n * 64);
        f32x4 z;
        z[0] = bfbits2f(zz.x & 0xffffu); z[1] = bfbits2f(zz.x >> 16);
        z[2] = bfbits2f(zz.y & 0xffffu); z[3] = bfbits2f(zz.y >> 16);
        s1 += z;
        s2 += z * z;
    }
    sh1[t] = s1;
    sh2[t] = s2;
    __syncthreads();
    int dbase = half * 64 + uld * 4;
    if (rg == 0) {
        #pragma unroll 8
        for (int k = 1; k < 64; ++k) { s1 += sh1[uld + 16 * k]; s2 += sh2[uld + 16 * k]; }
        int cnt = e - s;
        float cf = (float)(cnt > 0 ? cnt : 1);
        #pragma unroll
        for (int j = 0; j < 4; ++j) {
            float m = s1[j] / cf, ez = s2[j] / cf;
            float sc = scale[dbase + j];
            float var = fmaxf(ez - (2.0f - sc) * sc * m * m, 0.f);
            sa[uld * 4 + j] = m * sc;
            sb[uld * 4 + j] = weight[dbase + j] / sqrtf(var + GN_EPS);
        }
    }
    __syncthreads();
    float as0 = sa[uld * 4], as1 = sa[uld * 4 + 1], as2 = sa[uld * 4 + 2], as3 = sa[uld * 4 + 3];
    float bm0 = sb[uld * 4], bm1 = sb[uld * 4 + 1], bm2 = sb[uld * 4 + 2], bm3 = sb[uld * 4 + 3];
    float bi0 = bias[dbase], bi1 = bias[dbase + 1], bi2 = bias[dbase + 2], bi3 = bias[dbase + 3];
    unsigned* hp = Hb + half * 32 + uld * 2;
    for (int n = s + rg; n < e; n += 64) {
        uint2 zz = *(const uint2*)(zp + (size_t)n * 64);
        float z0 = bfbits2f(zz.x & 0xffffu), z1 = bfbits2f(zz.x >> 16);
        float z2 = bfbits2f(zz.y & 0xffffu), z3 = bfbits2f(zz.y >> 16);
        float o0 = fmaxf((z0 - as0) * bm0 + bi0, 0.f);
        float o1 = fmaxf((z1 - as1) * bm1 + bi1, 0.f);
        float o2 = fmaxf((z2 - as2) * bm2 + bi2, 0.f);
        float o3 = fmaxf((z3 - as3) * bm3 + bi3, 0.f);
        uint2 o;
        o.x = packbf2(o0, o1);
        o.y = packbf2(o2, o3);
        *(uint2*)(hp + (size_t)n * 64) = o;
    }
}

// ---------------- last layer: GraphNorm + relu + readout + final MLP + log_softmax ----------
__global__ __launch_bounds__(1024) void gn_last(const unsigned* __restrict__ Zb, const int* __restrict__ gstart,
                                                const float* __restrict__ scale, const float* __restrict__ weight,
                                                const float* __restrict__ bias,
                                                const float* __restrict__ fw1, const float* __restrict__ fb1,
                                                const float* __restrict__ fw2, const float* __restrict__ fb2,
                                                const float* __restrict__ fw3, const float* __restrict__ fb3,
                                                float* __restrict__ out) {
    __shared__ f32x4 sh1[1024], sh2[1024];
    __shared__ float sa[128], sb[128];
    __shared__ float v0[128], v1[128], v2[128], lg[10];
    int g = blockIdx.x;
    int t = threadIdx.x;
    int du = t & 31, rg = t >> 5;            // 32 uint2-cols x 32 row-groups
    int s = gstart[g], e = gstart[g + 1];
    const unsigned* zp = Zb + du * 2;
    f32x4 s1 = (f32x4)(0.f), s2 = (f32x4)(0.f);
    for (int n = s + rg; n < e; n += 32) {
        uint2 zz = *(const uint2*)(zp + (size_t)n * 64);
        f32x4 z;
        z[0] = bfbits2f(zz.x & 0xffffu); z[1] = bfbits2f(zz.x >> 16);
        z[2] = bfbits2f(zz.y & 0xffffu); z[3] = bfbits2f(zz.y >> 16);
        s1 += z;
        s2 += z * z;
    }
    sh1[t] = s1;
    sh2[t] = s2;
    __syncthreads();
    int dbase = du * 4;
    if (rg == 0) {
        #pragma unroll 8
        for (int k = 1; k < 32; ++k) { s1 += sh1[du + 32 * k]; s2 += sh2[du + 32 * k]; }
        int cnt = e - s;
        float cf = (float)(cnt > 0 ? cnt : 1);
        #pragma unroll
        for (int j = 0; j < 4; ++j) {
            float m = s1[j] / cf, ez = s2[j] / cf;
            float sc = scale[dbase + j];
            float var = fmaxf(ez - (2.0f - sc) * sc * m * m, 0.f);
            sa[dbase + j] = m * sc;
            sb[dbase + j] = weight[dbase + j] / sqrtf(var + GN_EPS);
        }
    }
    __syncthreads();
    float as_[4], bm_[4], bi_[4];
    #pragma unroll
    for (int j = 0; j < 4; ++j) {
        as_[j] = sa[dbase + j];
        bm_[j] = sb[dbase + j];
        bi_[j] = bias[dbase + j];
    }
    f32x4 rsum = (f32x4)(0.f);
    for (int n = s + rg; n < e; n += 32) {
        uint2 zz = *(const uint2*)(zp + (size_t)n * 64);
        float z0 = bfbits2f(zz.x & 0xffffu), z1 = bfbits2f(zz.x >> 16);
        float z2 = bfbits2f(zz.y & 0xffffu), z3 = bfbits2f(zz.y >> 16);
        rsum[0] += fmaxf((z0 - as_[0]) * bm_[0] + bi_[0], 0.f);
        rsum[1] += fmaxf((z1 - as_[1]) * bm_[1] + bi_[1], 0.f);
        rsum[2] += fmaxf((z2 - as_[2]) * bm_[2] + bi_[2], 0.f);
        rsum[3] += fmaxf((z3 - as_[3]) * bm_[3] + bi_[3], 0.f);
    }
    __syncthreads();
    sh1[t] = rsum;
    __syncthreads();
    if (rg == 0) {
        #pragma unroll 8
        for (int k = 1; k < 32; ++k) rsum += sh1[du + 32 * k];
        #pragma unroll
        for (int j = 0; j < 4; ++j) v0[dbase + j] = rsum[j];
    }
    __syncthreads();
    if (t < 128) {
        float acc = fb1[t];
        for (int d = 0; d < 128; ++d) acc += v0[d] * fw1[d * 128 + t];
        v1[t] = fmaxf(acc, 0.f);
    }
    __syncthreads();
    if (t < 128) {
        float acc = fb2[t];
        for (int d = 0; d < 128; ++d) acc += v1[d] * fw2[d * 128 + t];
        v2[t] = fmaxf(acc, 0.f);
    }
    __syncthreads();
    if (t < 10) {
        float acc = fb3[t];
        for (int d = 0; d < 128; ++d) acc += v2[d] * fw3[d * 10 + t];
        lg[t] = acc;
    }
    __syncthreads();
    if (t < 10) {
        float m = -1e30f;
        for (int c = 0; c < 10; ++c) m = fmaxf(m, lg[c]);
        float ssum = 0.f;
        for (int c = 0; c < 10; ++c) ssum += expf(lg[c] - m);
        out[g * 10 + t] = lg[t] - m - logf(ssum);
    }
}

extern "C" void kernel_launch(void* const* d_in, const int* in_sizes, int n_in,
                              void* d_out, int out_size, void* d_ws, size_t ws_size,
                              hipStream_t stream) {
    const float* x      = (const float*)d_in[0];
    const float* gin_w1 = (const float*)d_in[1];
    const float* gin_b1 = (const float*)d_in[2];
    const float* gin_w2 = (const float*)d_in[3];
    const float* gin_b2 = (const float*)d_in[4];
    const float* gn_w   = (const float*)d_in[5];
    const float* gn_b   = (const float*)d_in[6];
    const float* gn_s   = (const float*)d_in[7];
    const float* fw1    = (const float*)d_in[8];
    const float* fb1    = (const float*)d_in[9];
    const float* fw2    = (const float*)d_in[10];
    const float* fb2    = (const float*)d_in[11];
    const float* fw3    = (const float*)d_in[12];
    const float* fb3    = (const float*)d_in[13];
    const int*   eidx   = (const int*)d_in[14];
    const int*   batch  = (const int*)d_in[15];
    float* out = (float*)d_out;

    const int* esrc = eidx;
    const int* edst = eidx + N_EDGES;

    auto align_up = [](size_t v) { return (v + 255) & ~(size_t)255; };
    char* p = (char*)d_ws;
    unsigned* Hb = (unsigned*)p;   p += align_up((size_t)N_NODES * DIM * 2);
    unsigned* Tb = (unsigned*)p;   p += align_up((size_t)N_NODES * DIM * 2);
    unsigned* Zb = (unsigned*)p;   p += align_up((size_t)N_NODES * DIM * 2);
    ushort_t* WThi = (ushort_t*)p; p += align_up((size_t)8 * DIM * DIM * 2);
    ushort_t* WTlo = (ushort_t*)p; p += align_up((size_t)8 * DIM * DIM * 2);
    int* gstart = (int*)p;         p += align_up((N_GRAPHS + 1) * 4);
    int* cnts = (int*)p;           p += align_up((size_t)NB * B_CHUNK * 4);
    int* off = (int*)p;            p += align_up(((size_t)NB * B_CHUNK + 1) * 4);
    int* bsum = (int*)p;           p += align_up(64 * 4);
    unsigned* ebuf = (unsigned*)p; p += align_up((size_t)N_EDGES * 4);
    int* eoff = (int*)p;           p += align_up((N_NODES + 1) * 4);
    int* csr = (int*)p;            p += align_up((size_t)N_EDGES * 4);

    const int SCAN_N = NB * B_CHUNK;                      // 25088
    setup_misc<<<SETUP_BLKS, 256, 0, stream>>>((const float4*)x, (uint4*)Hb, gin_w1, gin_w2,
                                               WThi, WTlo, batch, gstart, edst, cnts);
    scan_local<<<SCAN_BLKS, 1024, 0, stream>>>(cnts, off, bsum, SCAN_N);
    p3_place<<<B_CHUNK, 256, 0, stream>>>(esrc, edst, off, bsum, ebuf);
    p4_csr<<<NB, 512, 0, stream>>>(ebuf, off, bsum, eoff, csr);

    const int mm_grid = (N_NODES + 255) / 256;  // 196 blocks <= 256 CUs
    for (int l = 0; l < N_LAYERS; ++l) {
        agg_bf16<<<(N_NODES + 3) / 4, 256, 0, stream>>>((const uint4*)Hb, eoff, csr, (uint4*)Tb);
        mm_layer<<<mm_grid, 512, 0, stream>>>((const ushort_t*)Tb,
            WThi + (size_t)(2 * l) * DIM * DIM, WTlo + (size_t)(2 * l) * DIM * DIM,
            WThi + (size_t)(2 * l + 1) * DIM * DIM, WTlo + (size_t)(2 * l + 1) * DIM * DIM,
            gin_b1 + l * DIM, gin_b2 + l * DIM, (ushort_t*)Zb);
        if (l == N_LAYERS - 1)
            gn_last<<<N_GRAPHS, 1024, 0, stream>>>(Zb, gstart, gn_s + l * DIM,
                gn_w + l * DIM, gn_b + l * DIM, fw1, fb1, fw2, fb2, fw3, fb3, out);
        else
            gn_fused<<<N_GRAPHS * 2, 1024, 0, stream>>>(Zb, gstart, gn_s + l * DIM,
                gn_w + l * DIM, gn_b + l * DIM, Hb);
    }
}